// Round 3
// baseline (221.880 us; speedup 1.0000x reference)
//
#include <hip/hip_runtime.h>

// Problem: N_FEAT=12, BATCH=64. Fully fused single-workgroup kernel.
//
// Identity: left = min(fl·W, fu·W), right = fu·W, where
//   W[m] = sum_{S subset m, S != 0} (-1)^{|m\S|} FM[S]
// (Moebius/inverse-zeta transform of FM over the 12-bit subset lattice).
// fmat is a deterministic 0/1 subset-parity indicator -> folded analytically,
// never read. d_ws never touched (W lives in LDS only).

#define NB 12
#define NMASK 4096   // 2^12
#define NTHREADS 1024
#define NWAVES 16    // 1024/64
#define XS_ELEMS (64 * 24)

__global__ __launch_bounds__(NTHREADS) void k_fused(
    const float* __restrict__ x,        // (64,24): [0..11]=xl, [12..23]=xu
    const float* __restrict__ ie_vars,  // (4094,1)
    float* __restrict__ out) {          // left(64) ++ right(64)
  __shared__ float g[NMASK];            // FM then W
  __shared__ float xs[XS_ELEMS];
  // Per-wave product tables: [wave][0]=lowL [1]=highL [2]=lowU [3]=highU
  __shared__ float tab[NWAVES][4][64];

  const int tid = threadIdx.x;
  const int lane = tid & 63;
  const int wave = tid >> 6;

  // ---- stage x (1536 floats > 1024 threads: MUST loop — round-2 bug) ----
  for (int i = tid; i < XS_ELEMS; i += NTHREADS) xs[i] = x[i];

  // ---- Phase A: FM scan as popcount-level DP ----
  // fm[m] = |v[m-1]| + max_{b in m, m^b >= 1} fm[m^b]; masks 1..4094.
  for (int level = 1; level <= NB; ++level) {
    for (int m = tid; m < NMASK; m += NTHREADS) {
      if (m >= 1 && m <= NMASK - 2 && __popc(m) == level) {
        float best = 0.0f;  // no valid predecessor -> 0 (matches ref)
#pragma unroll
        for (int b = 0; b < NB; ++b) {
          const int p = m - (1 << b);
          if ((m & (1 << b)) && p >= 1) best = fmaxf(best, g[p]);
        }
        g[m] = fabsf(ie_vars[m - 1]) + best;
      }
    }
    __syncthreads();
  }

  // ---- Phase B: FM = min(fm,1); FM[full]=1; FM[empty]=0 ----
  for (int m = tid; m < NMASK; m += NTHREADS) {
    float val;
    if (m == 0)              val = 0.0f;
    else if (m == NMASK - 1) val = 1.0f;
    else                     val = fminf(g[m], 1.0f);
    g[m] = val;
  }
  __syncthreads();

  // ---- Phase C: Moebius transform (12 butterfly passes) ----
  // Writes touch only masks WITH the bit, reads only WITHOUT -> no hazard.
#pragma unroll 1
  for (int b = 0; b < NB; ++b) {
    for (int m = tid; m < NMASK; m += NTHREADS) {
      if (m & (1 << b)) g[m] -= g[m ^ (1 << b)];
    }
    __syncthreads();
  }
  // g[] now holds W; g[0] == 0 (untouched by butterflies).

  // ---- Phase D: batch dots. Wave w handles rows w, w+16, w+32, w+48 ----
  // Mask split: low 6 bits = lane (features 0..5), high 6 bits = k (6..11).
#pragma unroll 1
  for (int iter = 0; iter < 4; ++iter) {
    const int row = wave + iter * NWAVES;
    const float* xr = &xs[row * 24];

    // Build this wave's 6-bit product tables: entry 'lane' = product of
    // x[feature b] over set bits b of lane.
    float pLL = 1.0f, pHL = 1.0f, pLU = 1.0f, pHU = 1.0f;
#pragma unroll
    for (int b = 0; b < 6; ++b) {
      if (lane & (1 << b)) {
        pLL *= xr[b];       // low  bits -> features 0..5 (lower)
        pHL *= xr[6 + b];   // high bits -> features 6..11 (lower)
        pLU *= xr[12 + b];  // low, upper
        pHU *= xr[18 + b];  // high, upper
      }
    }
    tab[wave][0][lane] = pLL;
    tab[wave][1][lane] = pHL;
    tab[wave][2][lane] = pLU;
    tab[wave][3][lane] = pHU;
    __syncthreads();  // lockstep across waves (same trip count); cheap+safe

    const float lowL = tab[wave][0][lane];
    const float lowU = tab[wave][2][lane];
    float A = 0.0f, B = 0.0f;  // A = fl.W, B = fu.W
#pragma unroll
    for (int k = 0; k < 64; ++k) {
      const float w = g[k * 64 + lane];      // bank=lane%32: 2-way, free
      const float hL = tab[wave][1][k];      // broadcast
      const float hU = tab[wave][3][k];      // broadcast
      A = fmaf(lowL * hL, w, A);
      B = fmaf(lowU * hU, w, B);
    }

    // Wave-internal reduction over 64 lanes.
#pragma unroll
    for (int off = 32; off > 0; off >>= 1) {
      A += __shfl_down(A, off);
      B += __shfl_down(B, off);
    }
    if (lane == 0) {
      out[row] = fminf(A, B);  // left
      out[64 + row] = B;       // right
    }
    __syncthreads();
  }
}

extern "C" void kernel_launch(void* const* d_in, const int* in_sizes, int n_in,
                              void* d_out, int out_size, void* d_ws,
                              size_t ws_size, hipStream_t stream) {
  const float* x  = (const float*)d_in[0];   // (64,24) fp32
  const float* ie = (const float*)d_in[1];   // (4094,1) fp32
  // d_in[2] (fmat) folded analytically; never read. d_ws never used.
  float* out = (float*)d_out;

  k_fused<<<1, NTHREADS, 0, stream>>>(x, ie, out);
}